// Round 19
// baseline (161.877 us; speedup 1.0000x reference)
//
#include <hip/hip_runtime.h>
#include <hip/hip_bf16.h>
#include <stdint.h>

typedef __attribute__((ext_vector_type(8))) short s16x8;
typedef __attribute__((ext_vector_type(4))) float f32x4;

#define MFMA16(a, b, c) __builtin_amdgcn_mfma_f32_16x16x32_bf16((a), (b), (c), 0, 0, 0)
#define SBAR() __builtin_amdgcn_s_barrier()

__device__ __forceinline__ void gl_lds16(const void* g, void* l) {
  __builtin_amdgcn_global_load_lds(
      (__attribute__((address_space(1))) void*)(void*)g,
      (__attribute__((address_space(3))) void*)l,
      16, 0, 0);
}

__device__ __forceinline__ unsigned short f2bf(float f) {
  union { float f; uint32_t u; } c; c.f = f;
  return (unsigned short)((c.u + 0x7FFFu + ((c.u >> 16) & 1u)) >> 16);
}

__device__ __forceinline__ f32x4 max4(f32x4 a, f32x4 b) {
  f32x4 c;
  c[0] = fmaxf(a[0], b[0]); c[1] = fmaxf(a[1], b[1]);
  c[2] = fmaxf(a[2], b[2]); c[3] = fmaxf(a[3], b[3]);
  return c;
}

// bijective XCD-aware block swizzle (m204)
__device__ __forceinline__ void xcd_swz(int GX, int GY, int& bx, int& by) {
  int nwg = GX * GY;
  int lid = by * GX + bx;
  int q = nwg >> 3, rm = nwg & 7;
  int xcd = lid & 7, off = lid >> 3;
  int nid = (xcd < rm ? xcd * (q + 1) : rm * (q + 1) + (xcd - rm) * q) + off;
  bx = nid % GX;
  by = nid / GX;
}

// ======= merged conv1d (0..767) + f32->bf16 cvt + bias-combine (last block) =======
__global__ __launch_bounds__(256) void cvt_conv(
    const float* __restrict__ x, unsigned short* __restrict__ x_bf, int na4,
    const float* __restrict__ wqkv, unsigned short* __restrict__ wqkv_bf, int nb4,
    const float* __restrict__ wproj, unsigned short* __restrict__ wproj_bf, int nc4,
    const float* __restrict__ cqw, const float* __restrict__ ckw,
    float* __restrict__ tcpq, float* __restrict__ tcpk,
    const float* __restrict__ bqkv, const float* __restrict__ cqb,
    const float* __restrict__ ckb, float* __restrict__ bias_comb, int last_bid) {
  const int tid = threadIdx.x;
  const int bid = blockIdx.x;
  if (bid < 768) {
    __shared__ float g[192][10];  // [ci_local][t+1], zero-padded both t-ends
    const int clip = bid / 96;
    const int rem = bid % 96;
    const int chunk = rem >> 2;  // 0..23 -> 32 co
    const int part = rem & 3;    // ci0 = part*192
    const int ci0 = part * 192;
    for (int i = tid; i < 192 * 8; i += 256) {
      int tt = i / 192, ci = i % 192;
      g[ci][tt + 1] = x[(size_t)(clip * 8 + tt) * 151296 + ci0 + ci];
    }
    for (int i = tid; i < 192; i += 256) { g[i][0] = 0.f; g[i][9] = 0.f; }
    __syncthreads();
    const int co = chunk * 32 + (tid >> 3);
    const int t = tid & 7;
    float aq = 0.f, ak = 0.f;
    const float* wqp = cqw + (size_t)co * 2304 + ci0 * 3;
    const float* wkp = ckw + (size_t)co * 2304 + ci0 * 3;
    for (int ci = 0; ci < 192; ++ci) {
      float g0 = g[ci][t], g1 = g[ci][t + 1], g2 = g[ci][t + 2];
      aq += g0 * wqp[ci * 3 + 0] + g1 * wqp[ci * 3 + 1] + g2 * wqp[ci * 3 + 2];
      ak += g0 * wkp[ci * 3 + 0] + g1 * wkp[ci * 3 + 1] + g2 * wkp[ci * 3 + 2];
    }
    int b = clip * 8 + t;
    tcpq[part * 49152 + b * 768 + co] = aq;
    tcpk[part * 49152 + b * 768 + co] = ak;
    return;
  }
  if (bid == last_bid) {  // bias_comb[c] = b_qkv[c] + conv bias per section
    for (int i = tid; i < 2304; i += 256) {
      float v = bqkv[i];
      if (i < 768) v += cqb[i];
      else if (i < 1536) v += ckb[i - 768];
      bias_comb[i] = v;
    }
    return;
  }
  int i = (bid - 768) * 256 + tid;
  const float* src; unsigned short* dst; int j;
  if (i < na4) { src = x; dst = x_bf; j = i; }
  else if (i < na4 + nb4) { src = wqkv; dst = wqkv_bf; j = i - na4; }
  else if (i < na4 + nb4 + nc4) { src = wproj; dst = wproj_bf; j = i - na4 - nb4; }
  else return;
  float4 v = ((const float4*)src)[j];
  ushort4 o;
  o.x = f2bf(v.x); o.y = f2bf(v.y); o.z = f2bf(v.z); o.w = f2bf(v.w);
  ((ushort4*)dst)[j] = o;
}

// ======= fused QKV-GEMM + attention, one block per (b,h), 1024 threads =======
// R14/R15/R18-verified structure (94.6us): 16 uniform waves = 4 waves/SIMD.
// Phase 1: 4Mx4N wave grid, acc[<=4][3]; Xs+Ws 3-buffer gl_lds staging,
// fully-unrolled K-loop, per-wave counted vmcnt. Phase 2: 13 q-tiles on
// waves 0..12 + setprio around MFMA clusters. tcb loader sums 4 conv
// partials + combined bias.
__global__ __launch_bounds__(1024, 4) void qkv_attn(
    const unsigned short* __restrict__ X,    // x_bf 12608x768
    const unsigned short* __restrict__ Wq,   // wqkv_bf 2304x768
    const float* __restrict__ bias,          // 2304 (combined qkv+conv bias)
    const float* __restrict__ tcpq, const float* __restrict__ tcpk,  // 4x64x768 partials
    unsigned short* __restrict__ O) {        // ao_bf 12608x768
  union __align__(16) Smem {
    struct {  // phase-1 staging: 150 KiB
      unsigned short Xs[3][208][64];
      unsigned short Ws[3][192][64];
    } st;
    struct {  // phase-2 attention: ~104 KiB
      unsigned short Qs[208][72];
      unsigned short Ks[208][72];
      unsigned short VTs[64][232];
      unsigned short Ps[13][16][40];
    } at;
  };
  __shared__ Smem U;
  __shared__ float tcb[3][64];  // fused bias (+tc)

  const int tid = threadIdx.x;
  const int w = tid >> 6, lane = tid & 63;  // w = 0..15
  int bx = blockIdx.x, by0 = 0;
  xcd_swz(gridDim.x, 1, bx, by0);  // 768 % 8 == 0: same-b heads share XCD
  const int b = bx / 12, h = bx % 12;

  if (tid < 192) {
    int sec = tid >> 6, d = tid & 63;
    float v = bias[sec * 768 + h * 64 + d];
    if (sec < 2) {
      const float* tp = (sec == 0) ? tcpq : tcpk;
      int idx = b * 768 + h * 64 + d;
#pragma unroll
      for (int p = 0; p < 4; ++p) v += tp[p * 49152 + idx];
    }
    tcb[sec][d] = v;
  }

  const int wm = w >> 2, wn = w & 3;   // 4M x 4N wave grid for phase 1
  const int r = lane & 15, gq = lane >> 4;
  const int lrow = lane >> 3;
  const int lsw = ((lane & 7) ^ (lrow & 7)) * 8;  // inverse-swizzled 16B slot (elems)
  const int mfn = (wm == 3) ? 4 : 3;   // wm 0..2: rows wm*48..+47; wm 3: 144..207

  f32x4 acc[4][3] = {};
  const size_t xbase = (size_t)b * 197 * 768;

  // wave-invariant pieces, computed once (full unroll keeps the rest imm)
  const int swzk[2] = { ((0 + gq) ^ (r & 7)) * 16, ((4 + gq) ^ (r & 7)) * 16 };
  const int rowA = (wm * 48 + r) * 128;  // byte offset of A base row
  const int rowB = (wn * 48 + r) * 128;  // byte offset of B base row

  auto stage = [&](int buf, int kc) {
#pragma unroll
    for (int j = 0; j < 2; ++j) {
      int c = w + j * 16;  // X chunks 0..25
      if (c < 26) {
        int row = c * 8 + lrow;
        gl_lds16(X + xbase + (size_t)row * 768 + kc * 64 + lsw,
                 (char*)&U.st.Xs[buf][0][0] + c * 1024);
      }
    }
#pragma unroll
    for (int j = 0; j < 2; ++j) {
      int c = w + j * 16;  // W chunks 0..23 (never straddle a 64-row section)
      if (c < 24) {
        int wrow = c * 8 + lrow;
        int sec = wrow >> 6;
        gl_lds16(Wq + (size_t)(sec * 768 + h * 64 + (wrow & 63)) * 768 + kc * 64 + lsw,
                 (char*)&U.st.Ws[buf][0][0] + c * 1024);
      }
    }
  };

#define WAIT_OWN()                                                 \
  do {                                                             \
    if (w < 8)       asm volatile("s_waitcnt vmcnt(4)" ::: "memory"); \
    else if (w < 10) asm volatile("s_waitcnt vmcnt(3)" ::: "memory"); \
    else             asm volatile("s_waitcnt vmcnt(2)" ::: "memory"); \
  } while (0)

  stage(0, 0);
  stage(1, 1);
  WAIT_OWN();  // tile 0 landed; tile 1 in flight
  SBAR();

#pragma unroll
  for (int kc = 0; kc < 12; ++kc) {  // FULL unroll: kc, kc%3, branches all imm
    if (kc + 2 < 12) stage((kc + 2) % 3, kc + 2);  // into free buffer
    const char* xb = (const char*)&U.st.Xs[kc % 3][0][0] + rowA;
    const char* wb = (const char*)&U.st.Ws[kc % 3][0][0] + rowB;
    __builtin_amdgcn_s_setprio(1);
#pragma unroll
    for (int kk = 0; kk < 2; ++kk) {
      s16x8 bfrg[3];
#pragma unroll
      for (int nf = 0; nf < 3; ++nf)
        bfrg[nf] = *(const s16x8*)(wb + nf * 2048 + swzk[kk]);
#pragma unroll
      for (int mf = 0; mf < 4; ++mf) {
        if (mf < mfn) {
          s16x8 afr = *(const s16x8*)(xb + mf * 2048 + swzk[kk]);
#pragma unroll
          for (int nf = 0; nf < 3; ++nf) acc[mf][nf] = MFMA16(afr, bfrg[nf], acc[mf][nf]);
        }
      }
    }
    __builtin_amdgcn_s_setprio(0);
    if (kc < 10) {  // own just-issued loads remain; tile kc+1 guaranteed landed
      WAIT_OWN();
      SBAR();
    } else if (kc == 10) {
      asm volatile("s_waitcnt vmcnt(0)" ::: "memory");
      SBAR();
    }
  }
  __syncthreads();  // all waves done reading tile 11 before union is repurposed

  // ---- epilogue: Q/K -> LDS row-major, V -> LDS transposed; zero V^T pad cols ----
  for (int i = tid; i < 64 * 35; i += 1024) {
    int d = i / 35, c = 197 + i % 35;
    U.at.VTs[d][c] = 0;
  }
#pragma unroll
  for (int mf = 0; mf < 4; ++mf) {
    if (mf < mfn) {
#pragma unroll
      for (int nf = 0; nf < 3; ++nf) {
        int ncol = wn * 48 + nf * 16 + r;
        int sec = ncol >> 6, d = ncol & 63;
        float bb = tcb[sec][d];
#pragma unroll
        for (int rr = 0; rr < 4; ++rr) {
          int mrow = wm * 48 + mf * 16 + gq * 4 + rr;
          unsigned short bv = f2bf(acc[mf][nf][rr] + bb);
          if (sec == 0)      U.at.Qs[mrow][d] = bv;
          else if (sec == 1) U.at.Ks[mrow][d] = bv;
          else if (mrow < 197) U.at.VTs[d][mrow] = bv;  // keep garbage V out of PV MFMA
        }
      }
    }
  }
  __syncthreads();

  // ---- phase 2: attention; waves 0..12 each own one 16-row q-tile ----
  const int g = gq;
  for (int qt = w; qt < 13; qt += 16) {
    const int q0 = qt * 16;
    int qrow = q0 + r; if (qrow > 196) qrow = 196;
    s16x8 aq0 = *(const s16x8*)&U.at.Qs[qrow][g * 8];
    s16x8 aq1 = *(const s16x8*)&U.at.Qs[qrow][32 + g * 8];

    f32x4 s[13];
    __builtin_amdgcn_s_setprio(1);
#pragma unroll
    for (int j = 0; j < 13; ++j) {
      f32x4 z = {};
      z = MFMA16(aq0, *(const s16x8*)&U.at.Ks[j * 16 + r][g * 8], z);
      z = MFMA16(aq1, *(const s16x8*)&U.at.Ks[j * 16 + r][32 + g * 8], z);
      s[j] = z;
    }
    __builtin_amdgcn_s_setprio(0);
    if (r >= 5) { s[12][0] = -1e30f; s[12][1] = -1e30f; s[12][2] = -1e30f; s[12][3] = -1e30f; }

    f32x4 mx = s[0];
#pragma unroll
    for (int j = 1; j < 13; ++j) mx = max4(mx, s[j]);
#pragma unroll
    for (int off = 1; off < 16; off <<= 1) {
      f32x4 o_;
      o_[0] = __shfl_xor(mx[0], off, 64); o_[1] = __shfl_xor(mx[1], off, 64);
      o_[2] = __shfl_xor(mx[2], off, 64); o_[3] = __shfl_xor(mx[3], off, 64);
      mx = max4(mx, o_);
    }
    const float cexp = 0.125f * 1.44269504088896f;  // scale * log2(e)
    f32x4 sum = {};
#pragma unroll
    for (int j = 0; j < 13; ++j) {
      f32x4 p;
      p[0] = exp2f((s[j][0] - mx[0]) * cexp); p[1] = exp2f((s[j][1] - mx[1]) * cexp);
      p[2] = exp2f((s[j][2] - mx[2]) * cexp); p[3] = exp2f((s[j][3] - mx[3]) * cexp);
      s[j] = p;
      sum += p;
    }
#pragma unroll
    for (int off = 1; off < 16; off <<= 1) {
      sum[0] += __shfl_xor(sum[0], off, 64); sum[1] += __shfl_xor(sum[1], off, 64);
      sum[2] += __shfl_xor(sum[2], off, 64); sum[3] += __shfl_xor(sum[3], off, 64);
    }

    f32x4 o4[4] = {};
    for (int ks = 0; ks < 7; ++ks) {
      int j0 = ks * 2;
#pragma unroll
      for (int jj = 0; jj < 2; ++jj) {
        int jt = j0 + jj;
        int colb = jj * 16 + r;
        if (jt < 13) {
          f32x4 p = s[jt < 13 ? jt : 0];
          U.at.Ps[w][g * 4 + 0][colb] = f2bf(p[0]);
          U.at.Ps[w][g * 4 + 1][colb] = f2bf(p[1]);
          U.at.Ps[w][g * 4 + 2][colb] = f2bf(p[2]);
          U.at.Ps[w][g * 4 + 3][colb] = f2bf(p[3]);
        } else {
          U.at.Ps[w][g * 4 + 0][colb] = 0; U.at.Ps[w][g * 4 + 1][colb] = 0;
          U.at.Ps[w][g * 4 + 2][colb] = 0; U.at.Ps[w][g * 4 + 3][colb] = 0;
        }
      }
      asm volatile("s_waitcnt lgkmcnt(0)" ::: "memory");  // wave-local P transpose RAW
      s16x8 ap = *(const s16x8*)&U.at.Ps[w][r][g * 8];
      __builtin_amdgcn_s_setprio(1);
#pragma unroll
      for (int n = 0; n < 4; ++n)
        o4[n] = MFMA16(ap, *(const s16x8*)&U.at.VTs[n * 16 + r][ks * 32 + g * 8], o4[n]);
      __builtin_amdgcn_s_setprio(0);
    }

    f32x4 rinv;
    rinv[0] = 1.0f / sum[0]; rinv[1] = 1.0f / sum[1];
    rinv[2] = 1.0f / sum[2]; rinv[3] = 1.0f / sum[3];
#pragma unroll
    for (int n = 0; n < 4; ++n) {
#pragma unroll
      for (int rr = 0; rr < 4; ++rr) {
        int qr = q0 + g * 4 + rr;
        if (qr < 197)
          O[((size_t)(b * 197 + qr)) * 768 + h * 64 + n * 16 + r] = f2bf(o4[n][rr] * rinv[rr]);
      }
    }
  }
#undef WAIT_OWN
}

// ======= projection GEMM v2: BM=BN=128, 512 thr, 65.5KB dbuf LDS -> 2 blocks/CU =======
// R4-verified depth-2 2-barrier skeleton scaled to 8 waves (2M x 4N, acc[4][2]).
// grid 6 x 99 = 594 blocks @ 2/CU; A-tile tail rows (M>=12608) read workspace
// (safe) and are write-masked.
__global__ __launch_bounds__(512, 4) void proj_gemm(
    const unsigned short* __restrict__ A,   // ao_bf 12608x768
    const unsigned short* __restrict__ Bw,  // wproj_bf 768x768
    const float* __restrict__ bias,         // 768
    float* __restrict__ Out) {
  __shared__ __align__(16) unsigned short As[2][128][64];
  __shared__ __align__(16) unsigned short Bs[2][128][64];
  const int tid = threadIdx.x;
  const int w = tid >> 6, lane = tid & 63;
  const int wm = w >> 2, wn = w & 3;   // 2M x 4N wave grid
  const int r = lane & 15, gq = lane >> 4;
  int bx = blockIdx.x, by = blockIdx.y;
  xcd_swz(gridDim.x, gridDim.y, bx, by);
  const int m0 = by * 128, n0 = bx * 128;
  const int lrow = lane >> 3;
  const int lsw = ((lane & 7) ^ (lrow & 7)) * 8;
  const int swzk[2] = { ((0 + gq) ^ (r & 7)) * 16, ((4 + gq) ^ (r & 7)) * 16 };
  const int rowA = (wm * 64 + r) * 128;
  const int rowB = (wn * 32 + r) * 128;

  f32x4 acc[4][2] = {};

  auto stage = [&](int buf, int kt) {  // 4 gl_lds per wave (2 A + 2 B)
#pragma unroll
    for (int j = 0; j < 2; ++j) {
      int c = w + j * 8;  // A chunks 0..15
      int row = c * 8 + lrow;
      gl_lds16(A + (size_t)(m0 + row) * 768 + kt * 64 + lsw, (char*)&As[buf][0][0] + c * 1024);
    }
#pragma unroll
    for (int j = 0; j < 2; ++j) {
      int c = w + j * 8;  // B chunks 0..15
      int row = c * 8 + lrow;
      gl_lds16(Bw + (size_t)(n0 + row) * 768 + kt * 64 + lsw, (char*)&Bs[buf][0][0] + c * 1024);
    }
  };

  stage(0, 0);
  stage(1, 1);
  asm volatile("s_waitcnt vmcnt(4)" ::: "memory");  // tile 0's 4 loads landed
  SBAR();

#pragma unroll
  for (int kt = 0; kt < 12; ++kt) {
    const int cur = kt & 1;
    const char* xb = (const char*)&As[cur][0][0] + rowA;
    const char* wb = (const char*)&Bs[cur][0][0] + rowB;
    s16x8 af[2][4], bfr[2][2];
#pragma unroll
    for (int kk = 0; kk < 2; ++kk) {
#pragma unroll
      for (int m = 0; m < 4; ++m) af[kk][m] = *(const s16x8*)(xb + m * 2048 + swzk[kk]);
#pragma unroll
      for (int n = 0; n < 2; ++n) bfr[kk][n] = *(const s16x8*)(wb + n * 2048 + swzk[kk]);
    }
    asm volatile("s_waitcnt lgkmcnt(0)" ::: "memory");
    __builtin_amdgcn_sched_barrier(0);  // rule 18: keep MFMA below the lgkmcnt
    SBAR();  // all waves done reading buf[cur]; safe to overwrite
    if (kt + 2 < 12) stage(cur, kt + 2);
    __builtin_amdgcn_s_setprio(1);
#pragma unroll
    for (int kk = 0; kk < 2; ++kk)
#pragma unroll
      for (int m = 0; m < 4; ++m)
#pragma unroll
        for (int n = 0; n < 2; ++n) acc[m][n] = MFMA16(af[kk][m], bfr[kk][n], acc[m][n]);
    __builtin_amdgcn_s_setprio(0);
    if (kt < 11) {
      if (kt < 10) asm volatile("s_waitcnt vmcnt(4)" ::: "memory");  // next tile landed
      else         asm volatile("s_waitcnt vmcnt(0)" ::: "memory");  // drain at tail
      SBAR();  // buf[kt+1] published
    }
  }

#pragma unroll
  for (int m = 0; m < 4; ++m) {
#pragma unroll
    for (int n = 0; n < 2; ++n) {
      int N = n0 + wn * 32 + n * 16 + r;
      float bb = bias[N];
#pragma unroll
      for (int rr = 0; rr < 4; ++rr) {
        int M = m0 + wm * 64 + m * 16 + gq * 4 + rr;
        if (M < 12608) Out[(size_t)M * 768 + N] = acc[m][n][rr] + bb;
      }
    }
  }
}

extern "C" void kernel_launch(void* const* d_in, const int* in_sizes, int n_in,
                              void* d_out, int out_size, void* d_ws, size_t ws_size,
                              hipStream_t stream) {
  const float* x       = (const float*)d_in[0];
  const float* w_qkv   = (const float*)d_in[1];
  const float* b_qkv   = (const float*)d_in[2];
  const float* w_proj  = (const float*)d_in[3];
  const float* b_proj  = (const float*)d_in[4];
  const float* conv_qw = (const float*)d_in[5];
  const float* conv_qb = (const float*)d_in[6];
  const float* conv_kw = (const float*)d_in[7];
  const float* conv_kb = (const float*)d_in[8];
  float* out = (float*)d_out;

  char* ws = (char*)d_ws;
  size_t off = 0;
  auto alloc = [&](size_t n) {
    char* p = ws + off;
    off = (off + n + 255) & ~(size_t)255;
    return p;
  };
  // order matters: OOB tile reads from x_bf / ao_bf tails must land inside the workspace
  unsigned short* x_bf    = (unsigned short*)alloc(12608ull * 768 * 2);
  unsigned short* ao_bf   = (unsigned short*)alloc(12608ull * 768 * 2);
  unsigned short* wqkv_bf = (unsigned short*)alloc(2304ull * 768 * 2);
  unsigned short* wproj_bf= (unsigned short*)alloc(768ull * 768 * 2);
  float* tcpq = (float*)alloc(4ull * 64 * 768 * 4);
  float* tcpk = (float*)alloc(4ull * 64 * 768 * 4);
  float* bias_comb = (float*)alloc(2304ull * 4);
  if (off > ws_size) return;  // workspace too small; fail visibly

  const int na4 = 2420736, nb4 = 442368, nc4 = 147456;  // FLOAT4 counts
  const int cvt_blocks = (na4 + nb4 + nc4 + 255) / 256;
  const int last_bid = 768 + cvt_blocks;
  cvt_conv<<<dim3(last_bid + 1), 256, 0, stream>>>(
      x, x_bf, na4, w_qkv, wqkv_bf, nb4, w_proj, wproj_bf, nc4,
      conv_qw, conv_kw, tcpq, tcpk,
      b_qkv, conv_qb, conv_kb, bias_comb, last_bid);
  qkv_attn<<<dim3(768), 1024, 0, stream>>>(x_bf, wqkv_bf, bias_comb, tcpq, tcpk, ao_bf);
  proj_gemm<<<dim3(6, 99), 512, 0, stream>>>(ao_bf, wproj_bf, b_proj, out);
}

// Round 20
// 149.898 us; speedup vs baseline: 1.0799x; 1.0799x over previous
//
#include <hip/hip_runtime.h>
#include <hip/hip_bf16.h>
#include <stdint.h>

typedef __attribute__((ext_vector_type(8))) short s16x8;
typedef __attribute__((ext_vector_type(4))) float f32x4;

#define MFMA16(a, b, c) __builtin_amdgcn_mfma_f32_16x16x32_bf16((a), (b), (c), 0, 0, 0)
#define SBAR() __builtin_amdgcn_s_barrier()

__device__ __forceinline__ void gl_lds16(const void* g, void* l) {
  __builtin_amdgcn_global_load_lds(
      (__attribute__((address_space(1))) void*)(void*)g,
      (__attribute__((address_space(3))) void*)l,
      16, 0, 0);
}

__device__ __forceinline__ unsigned short f2bf(float f) {
  union { float f; uint32_t u; } c; c.f = f;
  return (unsigned short)((c.u + 0x7FFFu + ((c.u >> 16) & 1u)) >> 16);
}

__device__ __forceinline__ f32x4 max4(f32x4 a, f32x4 b) {
  f32x4 c;
  c[0] = fmaxf(a[0], b[0]); c[1] = fmaxf(a[1], b[1]);
  c[2] = fmaxf(a[2], b[2]); c[3] = fmaxf(a[3], b[3]);
  return c;
}

// bijective XCD-aware block swizzle (m204)
__device__ __forceinline__ void xcd_swz(int GX, int GY, int& bx, int& by) {
  int nwg = GX * GY;
  int lid = by * GX + bx;
  int q = nwg >> 3, rm = nwg & 7;
  int xcd = lid & 7, off = lid >> 3;
  int nid = (xcd < rm ? xcd * (q + 1) : rm * (q + 1) + (xcd - rm) * q) + off;
  bx = nid % GX;
  by = nid / GX;
}

// ======= merged conv1d (0..767) + f32->bf16 cvt + bias-combine (last block) =======
__global__ __launch_bounds__(256) void cvt_conv(
    const float* __restrict__ x, unsigned short* __restrict__ x_bf, int na4,
    const float* __restrict__ wqkv, unsigned short* __restrict__ wqkv_bf, int nb4,
    const float* __restrict__ wproj, unsigned short* __restrict__ wproj_bf, int nc4,
    const float* __restrict__ cqw, const float* __restrict__ ckw,
    float* __restrict__ tcpq, float* __restrict__ tcpk,
    const float* __restrict__ bqkv, const float* __restrict__ cqb,
    const float* __restrict__ ckb, float* __restrict__ bias_comb, int last_bid) {
  const int tid = threadIdx.x;
  const int bid = blockIdx.x;
  if (bid < 768) {
    __shared__ float g[192][10];  // [ci_local][t+1], zero-padded both t-ends
    const int clip = bid / 96;
    const int rem = bid % 96;
    const int chunk = rem >> 2;  // 0..23 -> 32 co
    const int part = rem & 3;    // ci0 = part*192
    const int ci0 = part * 192;
    for (int i = tid; i < 192 * 8; i += 256) {
      int tt = i / 192, ci = i % 192;
      g[ci][tt + 1] = x[(size_t)(clip * 8 + tt) * 151296 + ci0 + ci];
    }
    for (int i = tid; i < 192; i += 256) { g[i][0] = 0.f; g[i][9] = 0.f; }
    __syncthreads();
    const int co = chunk * 32 + (tid >> 3);
    const int t = tid & 7;
    float aq = 0.f, ak = 0.f;
    const float* wqp = cqw + (size_t)co * 2304 + ci0 * 3;
    const float* wkp = ckw + (size_t)co * 2304 + ci0 * 3;
    for (int ci = 0; ci < 192; ++ci) {
      float g0 = g[ci][t], g1 = g[ci][t + 1], g2 = g[ci][t + 2];
      aq += g0 * wqp[ci * 3 + 0] + g1 * wqp[ci * 3 + 1] + g2 * wqp[ci * 3 + 2];
      ak += g0 * wkp[ci * 3 + 0] + g1 * wkp[ci * 3 + 1] + g2 * wkp[ci * 3 + 2];
    }
    int b = clip * 8 + t;
    tcpq[part * 49152 + b * 768 + co] = aq;
    tcpk[part * 49152 + b * 768 + co] = ak;
    return;
  }
  if (bid == last_bid) {  // bias_comb[c] = b_qkv[c] + conv bias per section
    for (int i = tid; i < 2304; i += 256) {
      float v = bqkv[i];
      if (i < 768) v += cqb[i];
      else if (i < 1536) v += ckb[i - 768];
      bias_comb[i] = v;
    }
    return;
  }
  int i = (bid - 768) * 256 + tid;
  const float* src; unsigned short* dst; int j;
  if (i < na4) { src = x; dst = x_bf; j = i; }
  else if (i < na4 + nb4) { src = wqkv; dst = wqkv_bf; j = i - na4; }
  else if (i < na4 + nb4 + nc4) { src = wproj; dst = wproj_bf; j = i - na4 - nb4; }
  else return;
  float4 v = ((const float4*)src)[j];
  ushort4 o;
  o.x = f2bf(v.x); o.y = f2bf(v.y); o.z = f2bf(v.z); o.w = f2bf(v.w);
  ((ushort4*)dst)[j] = o;
}

// ======= fused QKV-GEMM + attention, one block per (b,h), 1024 threads =======
// R14/R15/R18-verified structure (94.5us): 16 uniform waves = 4 waves/SIMD.
// Phase 1: 4Mx4N wave grid, acc[<=4][3]; Xs+Ws 3-buffer gl_lds staging,
// fully-unrolled K-loop, per-wave counted vmcnt. Phase 2: 13 q-tiles on
// waves 0..12 + setprio around MFMA clusters. tcb loader sums 4 conv
// partials + combined bias.
__global__ __launch_bounds__(1024, 4) void qkv_attn(
    const unsigned short* __restrict__ X,    // x_bf 12608x768
    const unsigned short* __restrict__ Wq,   // wqkv_bf 2304x768
    const float* __restrict__ bias,          // 2304 (combined qkv+conv bias)
    const float* __restrict__ tcpq, const float* __restrict__ tcpk,  // 4x64x768 partials
    unsigned short* __restrict__ O) {        // ao_bf 12608x768
  union __align__(16) Smem {
    struct {  // phase-1 staging: 150 KiB
      unsigned short Xs[3][208][64];
      unsigned short Ws[3][192][64];
    } st;
    struct {  // phase-2 attention: ~104 KiB
      unsigned short Qs[208][72];
      unsigned short Ks[208][72];
      unsigned short VTs[64][232];
      unsigned short Ps[13][16][40];
    } at;
  };
  __shared__ Smem U;
  __shared__ float tcb[3][64];  // fused bias (+tc)

  const int tid = threadIdx.x;
  const int w = tid >> 6, lane = tid & 63;  // w = 0..15
  int bx = blockIdx.x, by0 = 0;
  xcd_swz(gridDim.x, 1, bx, by0);  // 768 % 8 == 0: same-b heads share XCD
  const int b = bx / 12, h = bx % 12;

  if (tid < 192) {
    int sec = tid >> 6, d = tid & 63;
    float v = bias[sec * 768 + h * 64 + d];
    if (sec < 2) {
      const float* tp = (sec == 0) ? tcpq : tcpk;
      int idx = b * 768 + h * 64 + d;
#pragma unroll
      for (int p = 0; p < 4; ++p) v += tp[p * 49152 + idx];
    }
    tcb[sec][d] = v;
  }

  const int wm = w >> 2, wn = w & 3;   // 4M x 4N wave grid for phase 1
  const int r = lane & 15, gq = lane >> 4;
  const int lrow = lane >> 3;
  const int lsw = ((lane & 7) ^ (lrow & 7)) * 8;  // inverse-swizzled 16B slot (elems)
  const int mfn = (wm == 3) ? 4 : 3;   // wm 0..2: rows wm*48..+47; wm 3: 144..207

  f32x4 acc[4][3] = {};
  const size_t xbase = (size_t)b * 197 * 768;

  // wave-invariant pieces, computed once (full unroll keeps the rest imm)
  const int swzk[2] = { ((0 + gq) ^ (r & 7)) * 16, ((4 + gq) ^ (r & 7)) * 16 };
  const int rowA = (wm * 48 + r) * 128;  // byte offset of A base row
  const int rowB = (wn * 48 + r) * 128;  // byte offset of B base row

  auto stage = [&](int buf, int kc) {
#pragma unroll
    for (int j = 0; j < 2; ++j) {
      int c = w + j * 16;  // X chunks 0..25
      if (c < 26) {
        int row = c * 8 + lrow;
        gl_lds16(X + xbase + (size_t)row * 768 + kc * 64 + lsw,
                 (char*)&U.st.Xs[buf][0][0] + c * 1024);
      }
    }
#pragma unroll
    for (int j = 0; j < 2; ++j) {
      int c = w + j * 16;  // W chunks 0..23 (never straddle a 64-row section)
      if (c < 24) {
        int wrow = c * 8 + lrow;
        int sec = wrow >> 6;
        gl_lds16(Wq + (size_t)(sec * 768 + h * 64 + (wrow & 63)) * 768 + kc * 64 + lsw,
                 (char*)&U.st.Ws[buf][0][0] + c * 1024);
      }
    }
  };

#define WAIT_OWN()                                                 \
  do {                                                             \
    if (w < 8)       asm volatile("s_waitcnt vmcnt(4)" ::: "memory"); \
    else if (w < 10) asm volatile("s_waitcnt vmcnt(3)" ::: "memory"); \
    else             asm volatile("s_waitcnt vmcnt(2)" ::: "memory"); \
  } while (0)

  stage(0, 0);
  stage(1, 1);
  WAIT_OWN();  // tile 0 landed; tile 1 in flight
  SBAR();

#pragma unroll
  for (int kc = 0; kc < 12; ++kc) {  // FULL unroll: kc, kc%3, branches all imm
    if (kc + 2 < 12) stage((kc + 2) % 3, kc + 2);  // into free buffer
    const char* xb = (const char*)&U.st.Xs[kc % 3][0][0] + rowA;
    const char* wb = (const char*)&U.st.Ws[kc % 3][0][0] + rowB;
    __builtin_amdgcn_s_setprio(1);
#pragma unroll
    for (int kk = 0; kk < 2; ++kk) {
      s16x8 bfrg[3];
#pragma unroll
      for (int nf = 0; nf < 3; ++nf)
        bfrg[nf] = *(const s16x8*)(wb + nf * 2048 + swzk[kk]);
#pragma unroll
      for (int mf = 0; mf < 4; ++mf) {
        if (mf < mfn) {
          s16x8 afr = *(const s16x8*)(xb + mf * 2048 + swzk[kk]);
#pragma unroll
          for (int nf = 0; nf < 3; ++nf) acc[mf][nf] = MFMA16(afr, bfrg[nf], acc[mf][nf]);
        }
      }
    }
    __builtin_amdgcn_s_setprio(0);
    if (kc < 10) {  // own just-issued loads remain; tile kc+1 guaranteed landed
      WAIT_OWN();
      SBAR();
    } else if (kc == 10) {
      asm volatile("s_waitcnt vmcnt(0)" ::: "memory");
      SBAR();
    }
  }
  __syncthreads();  // all waves done reading tile 11 before union is repurposed

  // ---- epilogue: Q/K -> LDS row-major, V -> LDS transposed; zero V^T pad cols ----
  for (int i = tid; i < 64 * 35; i += 1024) {
    int d = i / 35, c = 197 + i % 35;
    U.at.VTs[d][c] = 0;
  }
#pragma unroll
  for (int mf = 0; mf < 4; ++mf) {
    if (mf < mfn) {
#pragma unroll
      for (int nf = 0; nf < 3; ++nf) {
        int ncol = wn * 48 + nf * 16 + r;
        int sec = ncol >> 6, d = ncol & 63;
        float bb = tcb[sec][d];
#pragma unroll
        for (int rr = 0; rr < 4; ++rr) {
          int mrow = wm * 48 + mf * 16 + gq * 4 + rr;
          unsigned short bv = f2bf(acc[mf][nf][rr] + bb);
          if (sec == 0)      U.at.Qs[mrow][d] = bv;
          else if (sec == 1) U.at.Ks[mrow][d] = bv;
          else if (mrow < 197) U.at.VTs[d][mrow] = bv;  // keep garbage V out of PV MFMA
        }
      }
    }
  }
  __syncthreads();

  // ---- phase 2: attention; waves 0..12 each own one 16-row q-tile ----
  const int g = gq;
  for (int qt = w; qt < 13; qt += 16) {
    const int q0 = qt * 16;
    int qrow = q0 + r; if (qrow > 196) qrow = 196;
    s16x8 aq0 = *(const s16x8*)&U.at.Qs[qrow][g * 8];
    s16x8 aq1 = *(const s16x8*)&U.at.Qs[qrow][32 + g * 8];

    f32x4 s[13];
    __builtin_amdgcn_s_setprio(1);
#pragma unroll
    for (int j = 0; j < 13; ++j) {
      f32x4 z = {};
      z = MFMA16(aq0, *(const s16x8*)&U.at.Ks[j * 16 + r][g * 8], z);
      z = MFMA16(aq1, *(const s16x8*)&U.at.Ks[j * 16 + r][32 + g * 8], z);
      s[j] = z;
    }
    __builtin_amdgcn_s_setprio(0);
    if (r >= 5) { s[12][0] = -1e30f; s[12][1] = -1e30f; s[12][2] = -1e30f; s[12][3] = -1e30f; }

    f32x4 mx = s[0];
#pragma unroll
    for (int j = 1; j < 13; ++j) mx = max4(mx, s[j]);
#pragma unroll
    for (int off = 1; off < 16; off <<= 1) {
      f32x4 o_;
      o_[0] = __shfl_xor(mx[0], off, 64); o_[1] = __shfl_xor(mx[1], off, 64);
      o_[2] = __shfl_xor(mx[2], off, 64); o_[3] = __shfl_xor(mx[3], off, 64);
      mx = max4(mx, o_);
    }
    const float cexp = 0.125f * 1.44269504088896f;  // scale * log2(e)
    f32x4 sum = {};
#pragma unroll
    for (int j = 0; j < 13; ++j) {
      f32x4 p;
      p[0] = exp2f((s[j][0] - mx[0]) * cexp); p[1] = exp2f((s[j][1] - mx[1]) * cexp);
      p[2] = exp2f((s[j][2] - mx[2]) * cexp); p[3] = exp2f((s[j][3] - mx[3]) * cexp);
      s[j] = p;
      sum += p;
    }
#pragma unroll
    for (int off = 1; off < 16; off <<= 1) {
      sum[0] += __shfl_xor(sum[0], off, 64); sum[1] += __shfl_xor(sum[1], off, 64);
      sum[2] += __shfl_xor(sum[2], off, 64); sum[3] += __shfl_xor(sum[3], off, 64);
    }

    f32x4 o4[4] = {};
    for (int ks = 0; ks < 7; ++ks) {
      int j0 = ks * 2;
#pragma unroll
      for (int jj = 0; jj < 2; ++jj) {
        int jt = j0 + jj;
        int colb = jj * 16 + r;
        if (jt < 13) {
          f32x4 p = s[jt < 13 ? jt : 0];
          U.at.Ps[w][g * 4 + 0][colb] = f2bf(p[0]);
          U.at.Ps[w][g * 4 + 1][colb] = f2bf(p[1]);
          U.at.Ps[w][g * 4 + 2][colb] = f2bf(p[2]);
          U.at.Ps[w][g * 4 + 3][colb] = f2bf(p[3]);
        } else {
          U.at.Ps[w][g * 4 + 0][colb] = 0; U.at.Ps[w][g * 4 + 1][colb] = 0;
          U.at.Ps[w][g * 4 + 2][colb] = 0; U.at.Ps[w][g * 4 + 3][colb] = 0;
        }
      }
      asm volatile("s_waitcnt lgkmcnt(0)" ::: "memory");  // wave-local P transpose RAW
      s16x8 ap = *(const s16x8*)&U.at.Ps[w][r][g * 8];
      __builtin_amdgcn_s_setprio(1);
#pragma unroll
      for (int n = 0; n < 4; ++n)
        o4[n] = MFMA16(ap, *(const s16x8*)&U.at.VTs[n * 16 + r][ks * 32 + g * 8], o4[n]);
      __builtin_amdgcn_s_setprio(0);
    }

    f32x4 rinv;
    rinv[0] = 1.0f / sum[0]; rinv[1] = 1.0f / sum[1];
    rinv[2] = 1.0f / sum[2]; rinv[3] = 1.0f / sum[3];
#pragma unroll
    for (int n = 0; n < 4; ++n) {
#pragma unroll
      for (int rr = 0; rr < 4; ++rr) {
        int qr = q0 + g * 4 + rr;
        if (qr < 197)
          O[((size_t)(b * 197 + qr)) * 768 + h * 64 + n * 16 + r] = f2bf(o4[n][rr] * rinv[rr]);
      }
    }
  }
#undef WAIT_OWN
}

// ======= projection GEMM: phase-1 clone, 208x192 per block, grid 256 = 1 round =======
__global__ __launch_bounds__(1024, 4) void proj_gemm(
    const unsigned short* __restrict__ A,   // ao_bf 12608x768
    const unsigned short* __restrict__ Bw,  // wproj_bf 768x768
    const float* __restrict__ bias,         // 768
    float* __restrict__ Out) {
  __shared__ __align__(16) unsigned short Xs[3][208][64];
  __shared__ __align__(16) unsigned short Ws[3][192][64];
  const int tid = threadIdx.x;
  const int w = tid >> 6, lane = tid & 63;
  int bx = blockIdx.x, by0 = 0;
  xcd_swz(gridDim.x, 1, bx, by0);  // 256 % 8 == 0: bijective
  const int b = bx >> 2, nt = bx & 3;
  const int wm = w >> 2, wn = w & 3;
  const int r = lane & 15, gq = lane >> 4;
  const int lrow = lane >> 3;
  const int lsw = ((lane & 7) ^ (lrow & 7)) * 8;
  const int mfn = (wm == 3) ? 4 : 3;

  f32x4 acc[4][3] = {};
  const size_t abase = (size_t)b * 197 * 768;
  const int swzk[2] = { ((0 + gq) ^ (r & 7)) * 16, ((4 + gq) ^ (r & 7)) * 16 };
  const int rowA = (wm * 48 + r) * 128;
  const int rowB = (wn * 48 + r) * 128;

  auto stage = [&](int buf, int kc) {
#pragma unroll
    for (int j = 0; j < 2; ++j) {
      int c = w + j * 16;  // A chunks 0..25 (rows b*197..+207; tail reads land in ws: safe)
      if (c < 26) {
        int row = c * 8 + lrow;
        gl_lds16(A + abase + (size_t)row * 768 + kc * 64 + lsw,
                 (char*)&Xs[buf][0][0] + c * 1024);
      }
    }
#pragma unroll
    for (int j = 0; j < 2; ++j) {
      int c = w + j * 16;  // W chunks 0..23 (rows nt*192..+191)
      if (c < 24) {
        int wrow = c * 8 + lrow;
        gl_lds16(Bw + (size_t)(nt * 192 + wrow) * 768 + kc * 64 + lsw,
                 (char*)&Ws[buf][0][0] + c * 1024);
      }
    }
  };

#define WAIT_OWN()                                                 \
  do {                                                             \
    if (w < 8)       asm volatile("s_waitcnt vmcnt(4)" ::: "memory"); \
    else if (w < 10) asm volatile("s_waitcnt vmcnt(3)" ::: "memory"); \
    else             asm volatile("s_waitcnt vmcnt(2)" ::: "memory"); \
  } while (0)

  stage(0, 0);
  stage(1, 1);
  WAIT_OWN();
  SBAR();

#pragma unroll
  for (int kc = 0; kc < 12; ++kc) {
    if (kc + 2 < 12) stage((kc + 2) % 3, kc + 2);
    const char* xb = (const char*)&Xs[kc % 3][0][0] + rowA;
    const char* wb = (const char*)&Ws[kc % 3][0][0] + rowB;
    __builtin_amdgcn_s_setprio(1);
#pragma unroll
    for (int kk = 0; kk < 2; ++kk) {
      s16x8 bfrg[3];
#pragma unroll
      for (int nf = 0; nf < 3; ++nf)
        bfrg[nf] = *(const s16x8*)(wb + nf * 2048 + swzk[kk]);
#pragma unroll
      for (int mf = 0; mf < 4; ++mf) {
        if (mf < mfn) {
          s16x8 afr = *(const s16x8*)(xb + mf * 2048 + swzk[kk]);
#pragma unroll
          for (int nf = 0; nf < 3; ++nf) acc[mf][nf] = MFMA16(afr, bfrg[nf], acc[mf][nf]);
        }
      }
    }
    __builtin_amdgcn_s_setprio(0);
    if (kc < 10) {
      WAIT_OWN();
      SBAR();
    } else if (kc == 10) {
      asm volatile("s_waitcnt vmcnt(0)" ::: "memory");
      SBAR();
    }
  }

#pragma unroll
  for (int mf = 0; mf < 4; ++mf) {
    if (mf < mfn) {
#pragma unroll
      for (int nf = 0; nf < 3; ++nf) {
        int N = nt * 192 + wn * 48 + nf * 16 + r;
        float bb = bias[N];
#pragma unroll
        for (int rr = 0; rr < 4; ++rr) {
          int mrow = wm * 48 + mf * 16 + gq * 4 + rr;
          if (mrow < 197)  // never write into the next b's rows
            Out[((size_t)(b * 197 + mrow)) * 768 + N] = acc[mf][nf][rr] + bb;
        }
      }
    }
  }
#undef WAIT_OWN
}

extern "C" void kernel_launch(void* const* d_in, const int* in_sizes, int n_in,
                              void* d_out, int out_size, void* d_ws, size_t ws_size,
                              hipStream_t stream) {
  const float* x       = (const float*)d_in[0];
  const float* w_qkv   = (const float*)d_in[1];
  const float* b_qkv   = (const float*)d_in[2];
  const float* w_proj  = (const float*)d_in[3];
  const float* b_proj  = (const float*)d_in[4];
  const float* conv_qw = (const float*)d_in[5];
  const float* conv_qb = (const float*)d_in[6];
  const float* conv_kw = (const float*)d_in[7];
  const float* conv_kb = (const float*)d_in[8];
  float* out = (float*)d_out;

  char* ws = (char*)d_ws;
  size_t off = 0;
  auto alloc = [&](size_t n) {
    char* p = ws + off;
    off = (off + n + 255) & ~(size_t)255;
    return p;
  };
  // order matters: OOB tile reads from x_bf / ao_bf tails must land inside the workspace
  unsigned short* x_bf    = (unsigned short*)alloc(12608ull * 768 * 2);
  unsigned short* ao_bf   = (unsigned short*)alloc(12608ull * 768 * 2);
  unsigned short* wqkv_bf = (unsigned short*)alloc(2304ull * 768 * 2);
  unsigned short* wproj_bf= (unsigned short*)alloc(768ull * 768 * 2);
  float* tcpq = (float*)alloc(4ull * 64 * 768 * 4);
  float* tcpk = (float*)alloc(4ull * 64 * 768 * 4);
  float* bias_comb = (float*)alloc(2304ull * 4);
  if (off > ws_size) return;  // workspace too small; fail visibly

  const int na4 = 2420736, nb4 = 442368, nc4 = 147456;  // FLOAT4 counts
  const int cvt_blocks = (na4 + nb4 + nc4 + 255) / 256;
  const int last_bid = 768 + cvt_blocks;
  cvt_conv<<<dim3(last_bid + 1), 256, 0, stream>>>(
      x, x_bf, na4, w_qkv, wqkv_bf, nb4, w_proj, wproj_bf, nc4,
      conv_qw, conv_kw, tcpq, tcpk,
      b_qkv, conv_qb, conv_kb, bias_comb, last_bid);
  qkv_attn<<<dim3(768), 1024, 0, stream>>>(x_bf, wqkv_bf, bias_comb, tcpq, tcpk, ao_bf);
  proj_gemm<<<dim3(256), 1024, 0, stream>>>(ao_bf, wproj_bf, b_proj, out);
}